// Round 5
// baseline (21.667 us; speedup 1.0000x reference)
//
#include <hip/hip_runtime.h>

// Exact reference semantics: (sign(t-0.5)+1)*0.5 -> {0, 0.5, 1}
__device__ __forceinline__ float binarize(float t) {
    float d = t - 0.5f;
    float s = (d > 0.0f) ? 1.0f : ((d < 0.0f) ? -1.0f : 0.0f);
    return (s + 1.0f) * 0.5f;
}

// Ternary code of binarize: 2*binarize(v) in {0,1,2}; 1 only when v==0.5.
__device__ __forceinline__ int tri(float v) {
    float d = v - 0.5f;
    return (d > 0.0f) ? 2 : ((d < 0.0f) ? 0 : 1);
}

typedef float f32x4 __attribute__((ext_vector_type(4)));

__global__ __launch_bounds__(256, 8) void Packetbnn_kernel(
    const float* __restrict__ x,       // [B, 5]
    const float* __restrict__ w_conv,  // [5, 5]
    const float* __restrict__ w_lin,   // [5]
    float* __restrict__ out,           // [B]
    int nquad,                         // B/4
    int nrows)                         // B
{
    // Per-row output is a pure function of the 5-trit input pattern.
    // All values are exact dyadic rationals (products/sums of {0,0.25,0.5,1},
    // magnitude <= 5) -> every evaluation order is bit-identical to the
    // reference. 243-entry LUT, ~1 KB LDS.
    __shared__ float lut[243];

    const int tid = threadIdx.x;
    if (tid < 243) {
        int n = tid;
        float xb[5];
#pragma unroll
        for (int k = 0; k < 5; ++k) { xb[k] = 0.5f * (float)(n % 3); n /= 3; }
        float acc = 0.0f;
#pragma unroll
        for (int o = 0; o < 5; ++o) {
            float c = 0.0f;
#pragma unroll
            for (int k = 0; k < 5; ++k) c += xb[k] * binarize(w_conv[o * 5 + k]);
            acc += binarize(c) * binarize(w_lin[o]);
        }
        lut[tid] = acc;
    }
    __syncthreads();

    const float4* xv = reinterpret_cast<const float4*>(x);
    f32x4* ov = reinterpret_cast<f32x4*>(out);
    const long stride = (long)gridDim.x * blockDim.x;

    for (long t = (long)blockIdx.x * blockDim.x + tid; t < nquad; t += stride) {
        const float4* p = xv + t * 5;
        float4 v0 = p[0], v1 = p[1], v2 = p[2], v3 = p[3], v4 = p[4];
        float r[20] = {v0.x, v0.y, v0.z, v0.w,
                       v1.x, v1.y, v1.z, v1.w,
                       v2.x, v2.y, v2.z, v2.w,
                       v3.x, v3.y, v3.z, v3.w,
                       v4.x, v4.y, v4.z, v4.w};
        float res[4];
#pragma unroll
        for (int q = 0; q < 4; ++q) {
            int idx = tri(r[q * 5 + 0])
                    + 3  * tri(r[q * 5 + 1])
                    + 9  * tri(r[q * 5 + 2])
                    + 27 * tri(r[q * 5 + 3])
                    + 81 * tri(r[q * 5 + 4]);
            res[q] = lut[idx];
        }
        f32x4 o4 = {res[0], res[1], res[2], res[3]};
        __builtin_nontemporal_store(o4, ov + t);
    }

    // Tail rows (nrows % 4 != 0) — normally dead (B = 4194304).
    if (blockIdx.x == 0 && tid == 0) {
        for (int row = nquad * 4; row < nrows; ++row) {
            int idx = 0, w = 1;
            for (int k = 0; k < 5; ++k) { idx += w * tri(x[(size_t)row * 5 + k]); w *= 3; }
            out[row] = lut[idx];
        }
    }
}

extern "C" void kernel_launch(void* const* d_in, const int* in_sizes, int n_in,
                              void* d_out, int out_size, void* d_ws, size_t ws_size,
                              hipStream_t stream) {
    const float* x      = (const float*)d_in[0];  // [B,1,1,5]
    const float* w_conv = (const float*)d_in[1];  // [5,1,1,5]
    const float* w_lin  = (const float*)d_in[2];  // [1,5]
    float* out = (float*)d_out;                   // [B,1]

    int nrows = out_size;          // B
    int nquad = nrows / 4;
    int threads = 256;
    long need = ((long)nquad + threads - 1) / threads;
    int blocks = (int)(need < 2048 ? (need < 1 ? 1 : need) : 2048);  // G11: 8 blocks/CU, grid-stride

    Packetbnn_kernel<<<blocks, threads, 0, stream>>>(x, w_conv, w_lin, out,
                                                     nquad, nrows);
}